// Round 11
// baseline (1088.908 us; speedup 1.0000x reference)
//
#include <hip/hip_runtime.h>
#include <hip/hip_bf16.h>

typedef __hip_bfloat16 bf16;
typedef unsigned short ushort_t;
typedef __attribute__((ext_vector_type(8))) short short8;
typedef __attribute__((ext_vector_type(4))) float f32x4;

#define NN 100000   // nodes
#define NE 640000   // edges
#define HD 128      // hidden
#define NB 391      // ceil(NN/256)
#define EMB_U 6250  // NN*16/256
#define HIST_U 2500 // NE/256
#define GEMM_U 782  // ceil(NN/128): 128-row tiles (verified 51.5us r9)
#define AGG_U 6250  // NN/16 (16 nodes per block, 16 lanes per node)
#define D_U 391     // aux blocks for d / d2
#define LDA 136     // padded LDS row (bf16): 2-way bank aliasing (free)

// Linearity: no activation => out = A^3 X W^3 + d2*(bW^2) + d*(bW) + b,
// d = A*1, d2 = A*d. 3 sparse aggs on bf16 X + ONE dense gemm with W^3
// (agg3 fused into the gemm tile: X3 lives only in LDS).
// Round 11: cooperative launch abandoned (2 container crashes + 1 spill).
// Instead: scan1+scan3+pos merged into ONE decoupled-lookback kernel
// (CUB-style; dynamic block ids via atomic ctr -> every spin targets a
// lower id, scheduled earlier -> deadlock-free; no grid.sync needed).
// CSR stays SORTED (r9 showed arbitrary order costs ~10us epack locality).
// Pipeline: memset | ehist | scanpos | agg1 | agg2 | gemmf = 6 ops (was 8).

__device__ __forceinline__ float bf2f(ushort_t u) {
    unsigned v = (unsigned)u << 16;
    return __builtin_bit_cast(float, v);
}
__device__ __forceinline__ ushort_t f2bf(float f) {
    bf16 h = __float2bfloat16(f);
    return *(ushort_t*)&h;
}

struct P {
    const int *nodef, *typef, *lenf, *lanef, *adj_src, *adj_dst;
    const float *adj_val, *node_emb, *type_emb, *len_emb, *lane_emb, *W, *bias;
    ushort_t *Xa, *Xb, *w2t, *w3t;    // w2t[n][k]=W2[k][n]; w3t[n][k]=W^3[k][n] bf16
    float *bw, *bw2, *d, *d2;
    int *cnt, *ctr, *done, *offs, *slots;
    unsigned *flagA;                  // lookback flags: hi2=state(0/1=A/2=P), lo30=value
    int2 *epack;                      // (src, bitcast(val)) per CSR slot
    float *outf;
};

// ---- merged launch: wchain (block 0) + hist (slot-saving) + embed ----
// (round-7 verified, ~52us) 33KB static LDS -> 4 blocks/CU.
// MFMA map: C[m][n]=sum_k A[m][k]B[k][n]; A-frag A[m=lane&15][k=quad*8+j];
// B-frag B[k][n=lane&15] from T-layout rows; C/D col=lane&15, row=quad*4+reg.
__global__ __launch_bounds__(256) void ehist_k(P p) {
    __shared__ ushort_t WtL[HD * HD];    // 32 KB: WtL[n*HD+k] = W[k][n] bf16
    __shared__ float bwS[HD];            // 512 B
    const int tid = threadIdx.x;
    if (blockIdx.x >= 1 + HIST_U) {
        // ---- embed ----
        const int idx = (blockIdx.x - 1 - HIST_U) * 256 + tid;   // < NN*16
        const int i = idx >> 4;
        const int c = (idx & 15) * 8;        // boundaries 16/48/64 divisible by 8
        const float* tbl; size_t base;
        if (c < 16)      { tbl = p.lane_emb; base = (size_t)p.lanef[i] * 16 + c; }
        else if (c < 48) { tbl = p.type_emb; base = (size_t)p.typef[i] * 32 + (c - 16); }
        else if (c < 64) { tbl = p.len_emb;  base = (size_t)p.lenf[i]  * 16 + (c - 48); }
        else             { tbl = p.node_emb; base = (size_t)p.nodef[i] * 64 + (c - 64); }
        const float4 f0 = *(const float4*)(tbl + base);
        const float4 f1 = *(const float4*)(tbl + base + 4);
        ushort_t u8[8] = { f2bf(f0.x), f2bf(f0.y), f2bf(f0.z), f2bf(f0.w),
                           f2bf(f1.x), f2bf(f1.y), f2bf(f1.z), f2bf(f1.w) };
        *(uint4*)(p.Xa + (size_t)i * HD + c) = *(uint4*)u8;
        return;
    }
    if (blockIdx.x >= 1) {
        // ---- hist: one int atomic per edge, SAVE the slot ----
        const int e = (blockIdx.x - 1) * 256 + tid;
        p.slots[e] = atomicAdd(&p.cnt[p.adj_dst[e]], 1);
        return;
    }
    // ---- block 0: W-chain, WtL staged from f32 W with on-the-fly transpose ----
    for (int i = tid; i < HD * HD / 4; i += 256) {
        const int k  = (i * 4) >> 7;      // W row
        const int n0 = (i * 4) & 127;     // W col (4 consecutive)
        const float4 f = *(const float4*)&p.W[(size_t)k * HD + n0];
        WtL[(n0 + 0) * HD + k] = f2bf(f.x);
        WtL[(n0 + 1) * HD + k] = f2bf(f.y);
        WtL[(n0 + 2) * HD + k] = f2bf(f.z);
        WtL[(n0 + 3) * HD + k] = f2bf(f.w);
    }
    __syncthreads();

    const int w = tid >> 6;
    const int ln = tid & 15;
    const int quad = (tid >> 4) & 3;
    const int koff = quad * 8;
    const f32x4 zero = {0.f, 0.f, 0.f, 0.f};

    short8 bfrg[2][4];
#pragma unroll
    for (int nt = 0; nt < 2; ++nt)
#pragma unroll
        for (int kc = 0; kc < 4; ++kc)
            bfrg[nt][kc] = *(const short8*)&WtL[(w * 32 + nt * 16 + ln) * HD + kc * 32 + koff];

    // W2 = W*W -> w2t global scratch (single block; L2 round-trip, cheap)
#pragma unroll
    for (int mt = 0; mt < 8; ++mt) {
        const int m = mt * 16 + ln;
        short8 afrg[4];
#pragma unroll
        for (int kc = 0; kc < 4; ++kc) {
            ushort_t a[8];
#pragma unroll
            for (int j = 0; j < 8; ++j)
                a[j] = WtL[(kc * 32 + koff + j) * HD + m];   // A[m][k] = Wt[k][m]
            afrg[kc] = *(short8*)a;
        }
        f32x4 acc[2] = {zero, zero};
#pragma unroll
        for (int nt = 0; nt < 2; ++nt)
#pragma unroll
            for (int kc = 0; kc < 4; ++kc)
                acc[nt] = __builtin_amdgcn_mfma_f32_16x16x32_bf16(
                        afrg[kc], bfrg[nt][kc], acc[nt], 0, 0, 0);
#pragma unroll
        for (int nt = 0; nt < 2; ++nt)
#pragma unroll
            for (int reg = 0; reg < 4; ++reg) {
                const int col = w * 32 + nt * 16 + ln;
                const int row = mt * 16 + quad * 4 + reg;
                p.w2t[col * HD + row] = f2bf(acc[nt][reg]);  // w2t[n][k]=W2[k][n]
            }
    }
    __syncthreads();   // vmcnt drained before barrier: w2t visible in-block

    // W3 = W2*W -> w3t ; A[m][k] = W2[m][k] = w2t[k][m]
#pragma unroll
    for (int mt = 0; mt < 8; ++mt) {
        const int m = mt * 16 + ln;
        short8 afrg[4];
#pragma unroll
        for (int kc = 0; kc < 4; ++kc) {
            ushort_t a[8];
#pragma unroll
            for (int j = 0; j < 8; ++j)
                a[j] = p.w2t[(kc * 32 + koff + j) * HD + m];
            afrg[kc] = *(short8*)a;
        }
        f32x4 acc[2] = {zero, zero};
#pragma unroll
        for (int nt = 0; nt < 2; ++nt)
#pragma unroll
            for (int kc = 0; kc < 4; ++kc)
                acc[nt] = __builtin_amdgcn_mfma_f32_16x16x32_bf16(
                        afrg[kc], bfrg[nt][kc], acc[nt], 0, 0, 0);
#pragma unroll
        for (int nt = 0; nt < 2; ++nt)
#pragma unroll
            for (int reg = 0; reg < 4; ++reg) {
                const int col = w * 32 + nt * 16 + ln;
                const int row = mt * 16 + quad * 4 + reg;
                p.w3t[col * HD + row] = f2bf(acc[nt][reg]);
            }
    }
    __syncthreads();

    // bw = b*W, then bw2 = bw*W (from LDS WtL)
    if (tid < HD) {
        float s = 0.f;
        for (int k = 0; k < HD; ++k) s += p.bias[k] * bf2f(WtL[tid * HD + k]);
        bwS[tid] = s;
        p.bw[tid] = s;
    }
    __syncthreads();
    if (tid < HD) {
        float s = 0.f;
        for (int k = 0; k < HD; ++k) s += bwS[k] * bf2f(WtL[tid * HD + k]);
        p.bw2[tid] = s;
    }
}

// ---- scanpos: decoupled-lookback exclusive scan (sorted CSR) + pos ----
// grid = HIST_U. Dynamic block id via atomic ctr (ids in scheduling order,
// so every spin targets an earlier-scheduled block -> deadlock-free).
// Blocks with id < NB own scan range [id*256, id*256+255]; ALL blocks then
// scatter pos unit id, spin-gated per-edge on the dst range's done flag.
__global__ __launch_bounds__(256) void scanpos_k(P p) {
    __shared__ int s[256];
    __shared__ int sb_sh, run_sh;
    const int tid = threadIdx.x;
    if (tid == 0) sb_sh = atomicAdd(p.ctr, 1);
    __syncthreads();
    const int b = sb_sh;

    if (b < NB) {
        const int idx = b * 256 + tid;
        const int v = (idx < NN) ? p.cnt[idx] : 0;
        s[tid] = v;
        __syncthreads();
        for (int o = 1; o < 256; o <<= 1) {               // inclusive LDS scan
            const int x = (tid >= o) ? s[tid - o] : 0;
            __syncthreads();
            s[tid] += x;
            __syncthreads();
        }
        const int total = s[255];
        if (tid == 0)   // publish aggregate (state 1)
            __atomic_store_n(&p.flagA[b], (1u << 30) | (unsigned)total, __ATOMIC_RELEASE);
        if (tid < 64) { // wave-0 parallel lookback over 64-wide windows
            int run = 0;
            if (b > 0) {
                int j = b - 1;
                for (;;) {
                    const int m = j - tid;                // lane 0 = highest index
                    unsigned f = 0;
                    if (m >= 0) {
                        do {
                            f = __atomic_load_n(&p.flagA[m], __ATOMIC_ACQUIRE);
                        } while ((f >> 30) == 0u);
                    }
                    const bool hasP = (m >= 0) && ((f >> 30) == 2u);
                    const unsigned long long pmask = __ballot(hasP);
                    int contrib;
                    if (pmask) {
                        const int plane = __ffsll(pmask) - 1;   // highest m with prefix
                        contrib = (m >= 0 && tid <= plane) ? (int)(f & 0x3FFFFFFFu) : 0;
                    } else {
                        contrib = (m >= 0) ? (int)(f & 0x3FFFFFFFu) : 0;
                    }
                    for (int o = 32; o; o >>= 1) contrib += __shfl_down(contrib, o);
                    contrib = __shfl(contrib, 0);
                    run += contrib;
                    if (pmask) break;
                    j -= 64;
                    if (j < 0) break;
                }
            }
            if (tid == 0) {   // publish inclusive prefix (state 2)
                __atomic_store_n(&p.flagA[b], (2u << 30) | (unsigned)(run + total), __ATOMIC_RELEASE);
                run_sh = run;
            }
        }
        __syncthreads();
        const int run = run_sh;
        if (idx <= NN) p.offs[idx] = run + s[tid] - v;    // exclusive offsets
        __syncthreads();
        __threadfence();                                  // release offs writes
        if (tid == 0) __atomic_store_n(&p.done[b], 1, __ATOMIC_RELEASE);
    }

    // ---- pos duty (unit = b): spin-gated on dst range's done flag ----
    const int e = b * 256 + tid;
    const int dst = p.adj_dst[e];
    const int r = dst >> 8;
    while (__atomic_load_n(&p.done[r], __ATOMIC_ACQUIRE) == 0)
        __builtin_amdgcn_s_sleep(2);
    __threadfence();                                      // acquire offs writes
    int2 pk;
    pk.x = p.adj_src[e];
    pk.y = __float_as_int(p.adj_val[e]);
    p.epack[p.offs[dst] + p.slots[e]] = pk;
}

// ---- sparse aggregation: Xout = A * Xin (pure, no W/b) ----
// 16 nodes per block, 16 lanes x ushort8 per node (256B/row coalesced),
// 4-deep unroll. aux blocks: aux==1 -> d = A*1 ; aux==2 -> d2 = A*d.
__global__ __launch_bounds__(256) void agg_k(P p, const ushort_t* __restrict__ Xin,
                                             ushort_t* __restrict__ Xout, int aux) {
    if (blockIdx.x >= AGG_U) {
        const int node = (blockIdx.x - AGG_U) * 256 + threadIdx.x;
        if (node < NN) {
            const int lo = p.offs[node], hi = p.offs[node + 1];
            float s = 0.f;
            if (aux == 1) {
                for (int j = lo; j < hi; ++j) s += __int_as_float(p.epack[j].y);
                p.d[node] = s;
            } else {
                for (int j = lo; j < hi; ++j) {
                    const int2 e = p.epack[j];
                    s += __int_as_float(e.y) * p.d[e.x];
                }
                p.d2[node] = s;
            }
        }
        return;
    }
    const int node = blockIdx.x * 16 + (threadIdx.x >> 4);
    const int lane = threadIdx.x & 15;
    const int c = lane * 8;
    const int lo = p.offs[node];
    const int hi = p.offs[node + 1];
    float a0[8], a1[8], a2[8], a3[8];
#pragma unroll
    for (int k = 0; k < 8; ++k) { a0[k] = a1[k] = a2[k] = a3[k] = 0.f; }
    int j = lo;
    for (; j + 3 < hi; j += 4) {
        const int2 e0 = p.epack[j], e1 = p.epack[j + 1];
        const int2 e2 = p.epack[j + 2], e3 = p.epack[j + 3];
        const short8 u0 = *(const short8*)(Xin + (size_t)e0.x * HD + c);
        const short8 u1 = *(const short8*)(Xin + (size_t)e1.x * HD + c);
        const short8 u2 = *(const short8*)(Xin + (size_t)e2.x * HD + c);
        const short8 u3 = *(const short8*)(Xin + (size_t)e3.x * HD + c);
        const float v0 = __int_as_float(e0.y), v1 = __int_as_float(e1.y);
        const float v2 = __int_as_float(e2.y), v3 = __int_as_float(e3.y);
#pragma unroll
        for (int k = 0; k < 8; ++k) {
            a0[k] += bf2f((ushort_t)u0[k]) * v0;
            a1[k] += bf2f((ushort_t)u1[k]) * v1;
            a2[k] += bf2f((ushort_t)u2[k]) * v2;
            a3[k] += bf2f((ushort_t)u3[k]) * v3;
        }
    }
    for (; j < hi; ++j) {
        const int2 e0 = p.epack[j];
        const float v0 = __int_as_float(e0.y);
        const short8 u0 = *(const short8*)(Xin + (size_t)e0.x * HD + c);
#pragma unroll
        for (int k = 0; k < 8; ++k) a0[k] += bf2f((ushort_t)u0[k]) * v0;
    }
    ushort_t u8[8];
#pragma unroll
    for (int k = 0; k < 8; ++k) u8[k] = f2bf((a0[k] + a1[k]) + (a2[k] + a3[k]));
    *(uint4*)(Xout + (size_t)node * HD + c) = *(uint4*)u8;
}

// ---- fused agg3 + gemm, 128-row tiles (verified 51.5us r9) ----
__global__ __launch_bounds__(256) void gemmf_k(P p, const ushort_t* __restrict__ X2) {
    __shared__ ushort_t Xs[128 * LDA];   // 34.8 KB
    const int tid = threadIdx.x;
    const int row0 = blockIdx.x * 128;

    // aggregation phase: 16 groups of 16 lanes, 8 rows per group
    {
        const int g = tid >> 4;
        const int lane = tid & 15;
        const int c = lane * 8;
        for (int mi = 0; mi < 8; ++mi) {
            const int m = g * 8 + mi;
            const int gm = row0 + m;
            float a0[8], a1[8], a2[8], a3[8];
#pragma unroll
            for (int k = 0; k < 8; ++k) { a0[k] = a1[k] = a2[k] = a3[k] = 0.f; }
            if (gm < NN) {
                const int lo = p.offs[gm];
                const int hi = p.offs[gm + 1];
                int j = lo;
                for (; j + 3 < hi; j += 4) {
                    const int2 e0 = p.epack[j], e1 = p.epack[j + 1];
                    const int2 e2 = p.epack[j + 2], e3 = p.epack[j + 3];
                    const short8 u0 = *(const short8*)(X2 + (size_t)e0.x * HD + c);
                    const short8 u1 = *(const short8*)(X2 + (size_t)e1.x * HD + c);
                    const short8 u2 = *(const short8*)(X2 + (size_t)e2.x * HD + c);
                    const short8 u3 = *(const short8*)(X2 + (size_t)e3.x * HD + c);
                    const float v0 = __int_as_float(e0.y), v1 = __int_as_float(e1.y);
                    const float v2 = __int_as_float(e2.y), v3 = __int_as_float(e3.y);
#pragma unroll
                    for (int k = 0; k < 8; ++k) {
                        a0[k] += bf2f((ushort_t)u0[k]) * v0;
                        a1[k] += bf2f((ushort_t)u1[k]) * v1;
                        a2[k] += bf2f((ushort_t)u2[k]) * v2;
                        a3[k] += bf2f((ushort_t)u3[k]) * v3;
                    }
                }
                for (; j < hi; ++j) {
                    const int2 e0 = p.epack[j];
                    const float v0 = __int_as_float(e0.y);
                    const short8 u0 = *(const short8*)(X2 + (size_t)e0.x * HD + c);
#pragma unroll
                    for (int k = 0; k < 8; ++k) a0[k] += bf2f((ushort_t)u0[k]) * v0;
                }
            }
            ushort_t u8[8];
#pragma unroll
            for (int k = 0; k < 8; ++k) u8[k] = f2bf((a0[k] + a1[k]) + (a2[k] + a3[k]));
            *(uint4*)&Xs[m * LDA + c] = *(uint4*)u8;
        }
    }

    const int w = tid >> 6;
    const int ln = tid & 15;
    const int quad = (tid >> 4) & 3;
    const int koff = quad * 8;
    const int col0 = w * 32 + ln;
    const int col1 = col0 + 16;

    short8 bfrg[2][4];
#pragma unroll
    for (int nt = 0; nt < 2; ++nt)
#pragma unroll
        for (int kc = 0; kc < 4; ++kc)
            bfrg[nt][kc] = *(const short8*)&p.w3t[(size_t)(w * 32 + nt * 16 + ln) * HD + kc * 32 + koff];

    const float bwc0 = p.bw[col0],  bwc1 = p.bw[col1];
    const float bw2c0 = p.bw2[col0], bw2c1 = p.bw2[col1];
    const float bc0 = p.bias[col0], bc1 = p.bias[col1];

    __syncthreads();

    const f32x4 zero = {0.f, 0.f, 0.f, 0.f};
#pragma unroll
    for (int mt = 0; mt < 8; ++mt) {
        short8 afrg[4];
#pragma unroll
        for (int kc = 0; kc < 4; ++kc)
            afrg[kc] = *(const short8*)&Xs[(mt * 16 + ln) * LDA + kc * 32 + koff];
        f32x4 acc[2] = {zero, zero};
#pragma unroll
        for (int nt = 0; nt < 2; ++nt)
#pragma unroll
            for (int kc = 0; kc < 4; ++kc)
                acc[nt] = __builtin_amdgcn_mfma_f32_16x16x32_bf16(
                        afrg[kc], bfrg[nt][kc], acc[nt], 0, 0, 0);
#pragma unroll
        for (int reg = 0; reg < 4; ++reg) {
            const int gm = row0 + mt * 16 + quad * 4 + reg;
            if (gm < NN) {
                const float dg = p.d[gm], d2g = p.d2[gm];
                p.outf[(size_t)gm * HD + col0] = acc[0][reg] + d2g * bw2c0 + dg * bwc0 + bc0;
                p.outf[(size_t)gm * HD + col1] = acc[1][reg] + d2g * bw2c1 + dg * bwc1 + bc1;
            }
        }
    }
}

extern "C" void kernel_launch(void* const* d_in, const int* in_sizes, int n_in,
                              void* d_out, int out_size, void* d_ws, size_t ws_size,
                              hipStream_t stream) {
    P p;
    p.nodef    = (const int*)d_in[0];
    p.typef    = (const int*)d_in[1];
    p.lenf     = (const int*)d_in[2];
    p.lanef    = (const int*)d_in[3];
    p.adj_src  = (const int*)d_in[4];
    p.adj_dst  = (const int*)d_in[5];
    p.adj_val  = (const float*)d_in[6];
    p.node_emb = (const float*)d_in[7];
    p.type_emb = (const float*)d_in[8];
    p.len_emb  = (const float*)d_in[9];
    p.lane_emb = (const float*)d_in[10];
    p.W        = (const float*)d_in[11];
    p.bias     = (const float*)d_in[12];
    p.outf     = (float*)d_out;

    const size_t xbytes = (size_t)NN * HD * 2;   // 25.6 MB bf16
    char* wp = (char*)d_ws;
    p.Xa    = (ushort_t*)wp; wp += xbytes;
    p.Xb    = (ushort_t*)wp; wp += xbytes;
    // --- zeroed-per-iteration region (single memset): cnt|ctr|flagA|done ---
    p.cnt   = (int*)wp;      wp += (size_t)NN * 4;   // 400000
    p.ctr   = (int*)wp;      wp += 16;
    p.flagA = (unsigned*)wp; wp += 1600;             // NB=391 flags, padded
    p.done  = (int*)wp;      wp += 1600;
    // ---------------------------------------------------------------------
    p.offs  = (int*)wp;      wp += 400016;           // NN+1 ints, padded
    p.slots = (int*)wp;      wp += (size_t)NE * 4;
    p.epack = (int2*)wp;     wp += (size_t)NE * 8;
    p.w2t   = (ushort_t*)wp; wp += 32768;
    p.w3t   = (ushort_t*)wp; wp += 32768;
    p.bw    = (float*)wp;    wp += 512;
    p.bw2   = (float*)wp;    wp += 512;
    p.d     = (float*)wp;    wp += (size_t)NN * 4;
    p.d2    = (float*)wp;    wp += (size_t)NN * 4;

    hipMemsetAsync(p.cnt, 0, (size_t)NN * 4 + 16 + 1600 + 1600, stream);
    ehist_k<<<1 + HIST_U + EMB_U, 256, 0, stream>>>(p);        // wchain+hist+embed
    scanpos_k<<<HIST_U, 256, 0, stream>>>(p);                  // scan+pos, one kernel
    agg_k<<<AGG_U + D_U, 256, 0, stream>>>(p, p.Xa, p.Xb, 1);  // X1 = A X0, d
    agg_k<<<AGG_U + D_U, 256, 0, stream>>>(p, p.Xb, p.Xa, 2);  // X2 = A X1, d2
    gemmf_k<<<GEMM_U, 256, 0, stream>>>(p, p.Xa);              // X3 in LDS + gemm
}

// Round 12
// 287.780 us; speedup vs baseline: 3.7838x; 3.7838x over previous
//
#include <hip/hip_runtime.h>
#include <hip/hip_bf16.h>

typedef __hip_bfloat16 bf16;
typedef unsigned short ushort_t;
typedef __attribute__((ext_vector_type(8))) short short8;
typedef __attribute__((ext_vector_type(4))) float f32x4;

#define NN 100000   // nodes
#define NE 640000   // edges
#define HD 128      // hidden
#define NB 391      // ceil(NN/256)
#define EMB_U 6250  // NN*16/256
#define HIST_U 2500 // NE/256
#define GEMM_U 782  // ceil(NN/128): 128-row tiles (r9 measured 51.5us)
#define AGG_U 6250  // NN/16 (16 nodes per block, 16 lanes per node)
#define D_U 391     // aux blocks for d / d2
#define LDA 136     // padded LDS row (bf16): 2-way bank aliasing (free)

// Linearity: no activation => out = A^3 X W^3 + d2*(bW^2) + d*(bW) + b,
// d = A*1, d2 = A*d. 3 sparse aggs on bf16 X + ONE dense gemm with W^3
// (agg3 fused into the gemm tile: X3 lives only in LDS).
// Round 12: consolidation. Launch-gap elimination abandoned after 4 failures
// (coop hang x2, coop spill 1103us, spin-gate cross-XCD stall 843us). This
// is the verified round-7 skeleton with the one measured upgrade r7 missed:
// gemmf at 128-row tiles (r9: 51.5us vs r7's 64-row 54.7us). All parts are
// individually profiled at their memory/atomic structural bounds.

__device__ __forceinline__ float bf2f(ushort_t u) {
    unsigned v = (unsigned)u << 16;
    return __builtin_bit_cast(float, v);
}
__device__ __forceinline__ ushort_t f2bf(float f) {
    bf16 h = __float2bfloat16(f);
    return *(ushort_t*)&h;
}

struct P {
    const int *nodef, *typef, *lenf, *lanef, *adj_src, *adj_dst;
    const float *adj_val, *node_emb, *type_emb, *len_emb, *lane_emb, *W, *bias;
    ushort_t *Xa, *Xb, *w2t, *w3t;    // w2t[n][k]=W2[k][n]; w3t[n][k]=W^3[k][n] bf16
    float *bw, *bw2, *d, *d2;
    int *cnt, *offs, *slots, *bsum;
    int2 *epack;                      // (src, bitcast(val)) per CSR slot
    float *outf;
};

// ---- merged launch: wchain (block 0) + hist (slot-saving) + embed ----
// All independent: wchain needs W only; hist needs adj_dst + zeroed cnt
// (memset); embed needs feature indices + tables. 33KB static LDS ->
// 4 blocks/CU (measured ~52us, occupancy ~36%).
// MFMA map: C[m][n]=sum_k A[m][k]B[k][n]; A-frag A[m=lane&15][k=quad*8+j];
// B-frag B[k][n=lane&15] from T-layout rows; C/D col=lane&15, row=quad*4+reg.
__global__ __launch_bounds__(256) void ehist_k(P p) {
    __shared__ ushort_t WtL[HD * HD];    // 32 KB: WtL[n*HD+k] = W[k][n] bf16
    __shared__ float bwS[HD];            // 512 B
    const int tid = threadIdx.x;
    if (blockIdx.x >= 1 + HIST_U) {
        // ---- embed ----
        const int idx = (blockIdx.x - 1 - HIST_U) * 256 + tid;   // < NN*16
        const int i = idx >> 4;
        const int c = (idx & 15) * 8;        // boundaries 16/48/64 divisible by 8
        const float* tbl; size_t base;
        if (c < 16)      { tbl = p.lane_emb; base = (size_t)p.lanef[i] * 16 + c; }
        else if (c < 48) { tbl = p.type_emb; base = (size_t)p.typef[i] * 32 + (c - 16); }
        else if (c < 64) { tbl = p.len_emb;  base = (size_t)p.lenf[i]  * 16 + (c - 48); }
        else             { tbl = p.node_emb; base = (size_t)p.nodef[i] * 64 + (c - 64); }
        const float4 f0 = *(const float4*)(tbl + base);
        const float4 f1 = *(const float4*)(tbl + base + 4);
        ushort_t u8[8] = { f2bf(f0.x), f2bf(f0.y), f2bf(f0.z), f2bf(f0.w),
                           f2bf(f1.x), f2bf(f1.y), f2bf(f1.z), f2bf(f1.w) };
        *(uint4*)(p.Xa + (size_t)i * HD + c) = *(uint4*)u8;
        return;
    }
    if (blockIdx.x >= 1) {
        // ---- hist: one int atomic per edge, SAVE the slot ----
        const int e = (blockIdx.x - 1) * 256 + tid;
        p.slots[e] = atomicAdd(&p.cnt[p.adj_dst[e]], 1);
        return;
    }
    // ---- block 0: W-chain. WtL staged from f32 W (coalesced float4 reads,
    // transposed LDS writes). ----
    for (int i = tid; i < HD * HD / 4; i += 256) {
        const int k  = (i * 4) >> 7;      // W row
        const int n0 = (i * 4) & 127;     // W col (4 consecutive)
        const float4 f = *(const float4*)&p.W[(size_t)k * HD + n0];
        WtL[(n0 + 0) * HD + k] = f2bf(f.x);
        WtL[(n0 + 1) * HD + k] = f2bf(f.y);
        WtL[(n0 + 2) * HD + k] = f2bf(f.z);
        WtL[(n0 + 3) * HD + k] = f2bf(f.w);
    }
    __syncthreads();

    const int w = tid >> 6;
    const int ln = tid & 15;
    const int quad = (tid >> 4) & 3;
    const int koff = quad * 8;
    const f32x4 zero = {0.f, 0.f, 0.f, 0.f};

    short8 bfrg[2][4];
#pragma unroll
    for (int nt = 0; nt < 2; ++nt)
#pragma unroll
        for (int kc = 0; kc < 4; ++kc)
            bfrg[nt][kc] = *(const short8*)&WtL[(w * 32 + nt * 16 + ln) * HD + kc * 32 + koff];

    // W2 = W*W -> w2t global scratch (single block; L2 round-trip, cheap)
#pragma unroll
    for (int mt = 0; mt < 8; ++mt) {
        const int m = mt * 16 + ln;
        short8 afrg[4];
#pragma unroll
        for (int kc = 0; kc < 4; ++kc) {
            ushort_t a[8];
#pragma unroll
            for (int j = 0; j < 8; ++j)
                a[j] = WtL[(kc * 32 + koff + j) * HD + m];   // A[m][k] = Wt[k][m]
            afrg[kc] = *(short8*)a;
        }
        f32x4 acc[2] = {zero, zero};
#pragma unroll
        for (int nt = 0; nt < 2; ++nt)
#pragma unroll
            for (int kc = 0; kc < 4; ++kc)
                acc[nt] = __builtin_amdgcn_mfma_f32_16x16x32_bf16(
                        afrg[kc], bfrg[nt][kc], acc[nt], 0, 0, 0);
#pragma unroll
        for (int nt = 0; nt < 2; ++nt)
#pragma unroll
            for (int reg = 0; reg < 4; ++reg) {
                const int col = w * 32 + nt * 16 + ln;
                const int row = mt * 16 + quad * 4 + reg;
                p.w2t[col * HD + row] = f2bf(acc[nt][reg]);  // w2t[n][k]=W2[k][n]
            }
    }
    __syncthreads();   // vmcnt drained before barrier: w2t visible in-block

    // W3 = W2*W -> w3t ; A[m][k] = W2[m][k] = w2t[k][m]
#pragma unroll
    for (int mt = 0; mt < 8; ++mt) {
        const int m = mt * 16 + ln;
        short8 afrg[4];
#pragma unroll
        for (int kc = 0; kc < 4; ++kc) {
            ushort_t a[8];
#pragma unroll
            for (int j = 0; j < 8; ++j)
                a[j] = p.w2t[(kc * 32 + koff + j) * HD + m];
            afrg[kc] = *(short8*)a;
        }
        f32x4 acc[2] = {zero, zero};
#pragma unroll
        for (int nt = 0; nt < 2; ++nt)
#pragma unroll
            for (int kc = 0; kc < 4; ++kc)
                acc[nt] = __builtin_amdgcn_mfma_f32_16x16x32_bf16(
                        afrg[kc], bfrg[nt][kc], acc[nt], 0, 0, 0);
#pragma unroll
        for (int nt = 0; nt < 2; ++nt)
#pragma unroll
            for (int reg = 0; reg < 4; ++reg) {
                const int col = w * 32 + nt * 16 + ln;
                const int row = mt * 16 + quad * 4 + reg;
                p.w3t[col * HD + row] = f2bf(acc[nt][reg]);
            }
    }
    __syncthreads();

    // bw = b*W, then bw2 = bw*W (from LDS WtL)
    if (tid < HD) {
        float s = 0.f;
        for (int k = 0; k < HD; ++k) s += p.bias[k] * bf2f(WtL[tid * HD + k]);
        bwS[tid] = s;
        p.bw[tid] = s;
    }
    __syncthreads();
    if (tid < HD) {
        float s = 0.f;
        for (int k = 0; k < HD; ++k) s += bwS[k] * bf2f(WtL[tid * HD + k]);
        p.bw2[tid] = s;
    }
}

// ---- CSR build (sorted; r9's arbitrary-order cost ~10us epack locality) ----

__global__ __launch_bounds__(256) void scan1_k(P p) {
    __shared__ int s[256];
    const int tid = threadIdx.x;
    const int idx = blockIdx.x * 256 + tid;
    s[tid] = (idx < NN) ? p.cnt[idx] : 0;
    __syncthreads();
    for (int o = 128; o; o >>= 1) {
        if (tid < o) s[tid] += s[tid + o];
        __syncthreads();
    }
    if (tid == 0) p.bsum[blockIdx.x] = s[0];
}

__global__ __launch_bounds__(256) void scan3_k(P p) {
    __shared__ int s[256];
    const int b = blockIdx.x;
    const int tid = threadIdx.x;
    int acc = 0;
    for (int i = tid; i < b; i += 256) acc += p.bsum[i];
    s[tid] = acc;
    __syncthreads();
    for (int o = 128; o; o >>= 1) {
        if (tid < o) s[tid] += s[tid + o];
        __syncthreads();
    }
    const int boffv = s[0];
    __syncthreads();
    const int idx = b * 256 + tid;
    int v = (idx < NN) ? p.cnt[idx] : 0;
    s[tid] = v;
    __syncthreads();
    for (int o = 1; o < 256; o <<= 1) {
        int x = (tid >= o) ? s[tid - o] : 0;
        __syncthreads();
        s[tid] += x;
        __syncthreads();
    }
    const int excl = s[tid] - v + boffv;
    if (idx <= NN) p.offs[idx] = excl;
}

// atomic-free: slot within row was captured during hist
__global__ __launch_bounds__(256) void pos_k(P p) {
    const int e = blockIdx.x * 256 + threadIdx.x;   // grid exactly HIST_U
    const int dst = p.adj_dst[e];
    int2 pk;
    pk.x = p.adj_src[e];
    pk.y = __float_as_int(p.adj_val[e]);
    p.epack[p.offs[dst] + p.slots[e]] = pk;
}

// ---- sparse aggregation: Xout = A * Xin (pure, no W/b) ----
// 16 nodes per block, 16 lanes x ushort8 per node (256B/row coalesced),
// 4-deep unroll. aux blocks: aux==1 -> d = A*1 ; aux==2 -> d2 = A*d.
__global__ __launch_bounds__(256) void agg_k(P p, const ushort_t* __restrict__ Xin,
                                             ushort_t* __restrict__ Xout, int aux) {
    if (blockIdx.x >= AGG_U) {
        const int node = (blockIdx.x - AGG_U) * 256 + threadIdx.x;
        if (node < NN) {
            const int lo = p.offs[node], hi = p.offs[node + 1];
            float s = 0.f;
            if (aux == 1) {
                for (int j = lo; j < hi; ++j) s += __int_as_float(p.epack[j].y);
                p.d[node] = s;
            } else {
                for (int j = lo; j < hi; ++j) {
                    const int2 e = p.epack[j];
                    s += __int_as_float(e.y) * p.d[e.x];
                }
                p.d2[node] = s;
            }
        }
        return;
    }
    const int node = blockIdx.x * 16 + (threadIdx.x >> 4);
    const int lane = threadIdx.x & 15;
    const int c = lane * 8;
    const int lo = p.offs[node];
    const int hi = p.offs[node + 1];
    float a0[8], a1[8], a2[8], a3[8];
#pragma unroll
    for (int k = 0; k < 8; ++k) { a0[k] = a1[k] = a2[k] = a3[k] = 0.f; }
    int j = lo;
    for (; j + 3 < hi; j += 4) {
        const int2 e0 = p.epack[j], e1 = p.epack[j + 1];
        const int2 e2 = p.epack[j + 2], e3 = p.epack[j + 3];
        const short8 u0 = *(const short8*)(Xin + (size_t)e0.x * HD + c);
        const short8 u1 = *(const short8*)(Xin + (size_t)e1.x * HD + c);
        const short8 u2 = *(const short8*)(Xin + (size_t)e2.x * HD + c);
        const short8 u3 = *(const short8*)(Xin + (size_t)e3.x * HD + c);
        const float v0 = __int_as_float(e0.y), v1 = __int_as_float(e1.y);
        const float v2 = __int_as_float(e2.y), v3 = __int_as_float(e3.y);
#pragma unroll
        for (int k = 0; k < 8; ++k) {
            a0[k] += bf2f((ushort_t)u0[k]) * v0;
            a1[k] += bf2f((ushort_t)u1[k]) * v1;
            a2[k] += bf2f((ushort_t)u2[k]) * v2;
            a3[k] += bf2f((ushort_t)u3[k]) * v3;
        }
    }
    for (; j < hi; ++j) {
        const int2 e0 = p.epack[j];
        const float v0 = __int_as_float(e0.y);
        const short8 u0 = *(const short8*)(Xin + (size_t)e0.x * HD + c);
#pragma unroll
        for (int k = 0; k < 8; ++k) a0[k] += bf2f((ushort_t)u0[k]) * v0;
    }
    ushort_t u8[8];
#pragma unroll
    for (int k = 0; k < 8; ++k) u8[k] = f2bf((a0[k] + a1[k]) + (a2[k] + a3[k]));
    *(uint4*)(Xout + (size_t)node * HD + c) = *(uint4*)u8;
}

// ---- fused agg3 + gemm, 128-row tiles (r9 measured 51.5us): Xs = A*X2 in
// LDS, then out = Xs * W^3 + d2*(bW^2) + d*(bW) + b, f32 coalesced ----
__global__ __launch_bounds__(256) void gemmf_k(P p, const ushort_t* __restrict__ X2) {
    __shared__ ushort_t Xs[128 * LDA];   // 34.8 KB
    const int tid = threadIdx.x;
    const int row0 = blockIdx.x * 128;

    // aggregation phase: 16 groups of 16 lanes, 8 rows per group
    {
        const int g = tid >> 4;
        const int lane = tid & 15;
        const int c = lane * 8;
        for (int mi = 0; mi < 8; ++mi) {
            const int m = g * 8 + mi;
            const int gm = row0 + m;
            float a0[8], a1[8], a2[8], a3[8];
#pragma unroll
            for (int k = 0; k < 8; ++k) { a0[k] = a1[k] = a2[k] = a3[k] = 0.f; }
            if (gm < NN) {
                const int lo = p.offs[gm];
                const int hi = p.offs[gm + 1];
                int j = lo;
                for (; j + 3 < hi; j += 4) {
                    const int2 e0 = p.epack[j], e1 = p.epack[j + 1];
                    const int2 e2 = p.epack[j + 2], e3 = p.epack[j + 3];
                    const short8 u0 = *(const short8*)(X2 + (size_t)e0.x * HD + c);
                    const short8 u1 = *(const short8*)(X2 + (size_t)e1.x * HD + c);
                    const short8 u2 = *(const short8*)(X2 + (size_t)e2.x * HD + c);
                    const short8 u3 = *(const short8*)(X2 + (size_t)e3.x * HD + c);
                    const float v0 = __int_as_float(e0.y), v1 = __int_as_float(e1.y);
                    const float v2 = __int_as_float(e2.y), v3 = __int_as_float(e3.y);
#pragma unroll
                    for (int k = 0; k < 8; ++k) {
                        a0[k] += bf2f((ushort_t)u0[k]) * v0;
                        a1[k] += bf2f((ushort_t)u1[k]) * v1;
                        a2[k] += bf2f((ushort_t)u2[k]) * v2;
                        a3[k] += bf2f((ushort_t)u3[k]) * v3;
                    }
                }
                for (; j < hi; ++j) {
                    const int2 e0 = p.epack[j];
                    const float v0 = __int_as_float(e0.y);
                    const short8 u0 = *(const short8*)(X2 + (size_t)e0.x * HD + c);
#pragma unroll
                    for (int k = 0; k < 8; ++k) a0[k] += bf2f((ushort_t)u0[k]) * v0;
                }
            }
            ushort_t u8[8];
#pragma unroll
            for (int k = 0; k < 8; ++k) u8[k] = f2bf((a0[k] + a1[k]) + (a2[k] + a3[k]));
            *(uint4*)&Xs[m * LDA + c] = *(uint4*)u8;
        }
    }

    const int w = tid >> 6;
    const int ln = tid & 15;
    const int quad = (tid >> 4) & 3;
    const int koff = quad * 8;
    const int col0 = w * 32 + ln;
    const int col1 = col0 + 16;

    short8 bfrg[2][4];
#pragma unroll
    for (int nt = 0; nt < 2; ++nt)
#pragma unroll
        for (int kc = 0; kc < 4; ++kc)
            bfrg[nt][kc] = *(const short8*)&p.w3t[(size_t)(w * 32 + nt * 16 + ln) * HD + kc * 32 + koff];

    const float bwc0 = p.bw[col0],  bwc1 = p.bw[col1];
    const float bw2c0 = p.bw2[col0], bw2c1 = p.bw2[col1];
    const float bc0 = p.bias[col0], bc1 = p.bias[col1];

    __syncthreads();

    const f32x4 zero = {0.f, 0.f, 0.f, 0.f};
#pragma unroll
    for (int mt = 0; mt < 8; ++mt) {
        short8 afrg[4];
#pragma unroll
        for (int kc = 0; kc < 4; ++kc)
            afrg[kc] = *(const short8*)&Xs[(mt * 16 + ln) * LDA + kc * 32 + koff];
        f32x4 acc[2] = {zero, zero};
#pragma unroll
        for (int nt = 0; nt < 2; ++nt)
#pragma unroll
            for (int kc = 0; kc < 4; ++kc)
                acc[nt] = __builtin_amdgcn_mfma_f32_16x16x32_bf16(
                        afrg[kc], bfrg[nt][kc], acc[nt], 0, 0, 0);
#pragma unroll
        for (int reg = 0; reg < 4; ++reg) {
            const int gm = row0 + mt * 16 + quad * 4 + reg;
            if (gm < NN) {
                const float dg = p.d[gm], d2g = p.d2[gm];
                p.outf[(size_t)gm * HD + col0] = acc[0][reg] + d2g * bw2c0 + dg * bwc0 + bc0;
                p.outf[(size_t)gm * HD + col1] = acc[1][reg] + d2g * bw2c1 + dg * bwc1 + bc1;
            }
        }
    }
}

extern "C" void kernel_launch(void* const* d_in, const int* in_sizes, int n_in,
                              void* d_out, int out_size, void* d_ws, size_t ws_size,
                              hipStream_t stream) {
    P p;
    p.nodef    = (const int*)d_in[0];
    p.typef    = (const int*)d_in[1];
    p.lenf     = (const int*)d_in[2];
    p.lanef    = (const int*)d_in[3];
    p.adj_src  = (const int*)d_in[4];
    p.adj_dst  = (const int*)d_in[5];
    p.adj_val  = (const float*)d_in[6];
    p.node_emb = (const float*)d_in[7];
    p.type_emb = (const float*)d_in[8];
    p.len_emb  = (const float*)d_in[9];
    p.lane_emb = (const float*)d_in[10];
    p.W        = (const float*)d_in[11];
    p.bias     = (const float*)d_in[12];
    p.outf     = (float*)d_out;

    const size_t xbytes = (size_t)NN * HD * 2;   // 25.6 MB bf16
    char* wp = (char*)d_ws;
    p.Xa    = (ushort_t*)wp; wp += xbytes;
    p.Xb    = (ushort_t*)wp; wp += xbytes;
    p.cnt   = (int*)wp;      wp += (size_t)NN * 4;
    p.offs  = (int*)wp;      wp += 400016;            // NN+1 ints, padded
    p.slots = (int*)wp;      wp += (size_t)NE * 4;
    p.epack = (int2*)wp;     wp += (size_t)NE * 8;
    p.w2t   = (ushort_t*)wp; wp += 32768;
    p.w3t   = (ushort_t*)wp; wp += 32768;
    p.bw    = (float*)wp;    wp += 512;
    p.bw2   = (float*)wp;    wp += 512;
    p.d     = (float*)wp;    wp += (size_t)NN * 4;
    p.d2    = (float*)wp;    wp += (size_t)NN * 4;
    p.bsum  = (int*)wp;      wp += 1600;

    hipMemsetAsync(p.cnt, 0, (size_t)NN * 4, stream);      // cnt zero
    ehist_k<<<1 + HIST_U + EMB_U, 256, 0, stream>>>(p);    // wchain+hist+embed
    scan1_k<<<NB, 256, 0, stream>>>(p);
    scan3_k<<<NB, 256, 0, stream>>>(p);
    pos_k<<<HIST_U, 256, 0, stream>>>(p);
    agg_k<<<AGG_U + D_U, 256, 0, stream>>>(p, p.Xa, p.Xb, 1);  // X1 = A X0, d
    agg_k<<<AGG_U + D_U, 256, 0, stream>>>(p, p.Xb, p.Xa, 2);  // X2 = A X1, d2
    gemmf_k<<<GEMM_U, 256, 0, stream>>>(p, p.Xa);              // X3 in LDS + gemm
}